// Round 11
// baseline (51.403 us; speedup 1.0000x reference)
//
#include <hip/hip_runtime.h>
#include <math.h>

#define NBQ 50
#define S1 51
#define NPTS 2601      // 51*51
#define IN_D 64
#define HID 128
#define BSZ 256
#define NCHUNK 4
#define NUMAX 41       // max tiles per chunk (c<3: 41, c==3: 40)

typedef __bf16 bf16x8 __attribute__((ext_vector_type(8)));
typedef float  f32x4  __attribute__((ext_vector_type(4)));
typedef unsigned int u32x4 __attribute__((ext_vector_type(4)));

// ws layout (floats)
#define WS_CC     0                    // 51
#define WS_STEPS  64                   // 51
#define WS_XMAX   128                  // 1
#define WS_BASE   256                  // 256*128 = 32768
#define WS_SCAL   33024                // 256
#define WS_OFF    33280                // 256
#define WS_PART   33536                // 1024 blocks * 1 = 4096 slots reserved
#define WS_W1BF   41728                // 16384 bf16 = 8192 floats -> ends 49920

static __device__ inline unsigned int cvt_pk_bf16(float lo, float hi) {
    unsigned int r;
    asm("v_cvt_pk_bf16_f32 %0, %1, %2" : "=v"(r) : "v"(lo), "v"(hi));
    return r;
}

// ---------------- prep: w1 fragment conversion + cc/steps/xmax + base + n-net
__global__ void k_prep(const float* __restrict__ x, const float* __restrict__ h,
                       const float* __restrict__ iw0, const float* __restrict__ ib0,
                       const float* __restrict__ iw1,
                       const float* __restrict__ nw0, const float* __restrict__ nb0,
                       const float* __restrict__ nw1, const float* __restrict__ nb1,
                       const float* __restrict__ nw2, const float* __restrict__ nb2,
                       float* __restrict__ ws) {
    int blk = blockIdx.x;
    int tid = threadIdx.x;

    if (blk < 64) {
        // A-frag order: idx = ((NT*4+kk)*64 + lane)*8 + e
        //  value = iw1[(kk*32 + (lane>>4)*8 + e)*128 + NT*16 + (lane&15)]
        int idx  = blk * 256 + tid;      // 0..16383
        int e    = idx & 7;
        int lane = (idx >> 3) & 63;
        int fk   = idx >> 9;             // 0..31
        int kk   = fk & 3;
        int nt   = fk >> 2;
        int k = kk * 32 + (lane >> 4) * 8 + e;
        int n = nt * 16 + (lane & 15);
        __bf16* w1bf = (__bf16*)(ws + WS_W1BF);
        w1bf[idx] = (__bf16)iw1[k * HID + n];
        return;
    }

    __shared__ float s_steps[S1];
    __shared__ float s_red[4];
    __shared__ float s_h[IN_D - 1];
    __shared__ float s_o0[HID];
    __shared__ float s_part[4];

    if (blk == 64) {
        int t = tid;
        if (t < S1) {
            double st = cos((double)t * M_PI / (double)NBQ);
            s_steps[t] = (float)st;
            ws[WS_STEPS + t] = (float)st;
            double acc = 0.0;
            for (int i = 0; i <= NBQ; ++i) {
                double Wi;
                if (i == 0)       Wi = 1.0;
                else if (i & 1)   Wi = 0.0;
                else              Wi = 2.0 / (1.0 - (double)i * (double)i);
                double lam;
                if (t == 0)  lam = 0.5;
                else         lam = cos((double)i * (double)t * M_PI / (double)NBQ);
                if (t == NBQ) lam *= 0.5;
                lam *= 2.0 / (double)NBQ;
                acc += lam * Wi;
            }
            ws[WS_CC + t] = (float)acc;
        }
        __syncthreads();
        float xb = x[t];
        float m = -1e30f;
        for (int i = 0; i < S1; ++i)
            m = fmaxf(m, xb * (s_steps[i] + 1.0f) * 0.5f);
        for (int off = 32; off > 0; off >>= 1)
            m = fmaxf(m, __shfl_down(m, off));
        if ((t & 63) == 0) s_red[t >> 6] = m;
        __syncthreads();
        if (t == 0) {
            float mm = fmaxf(fmaxf(s_red[0], s_red[1]), fmaxf(s_red[2], s_red[3]));
            ws[WS_XMAX] = mm + 10.0f;
        }
        return;
    }

    // ---- base[b] + n-network: b = blk - 65, first 128 threads active ----
    int b = blk - 65;
    int n = tid;
    bool act = (n < HID);
    if (act && n < IN_D - 1) s_h[n] = h[b * (IN_D - 1) + n];
    __syncthreads();
    float o1 = 0.0f;
    if (act) {
        float accB = ib0[n];
        float acc0 = nb0[n];
        for (int d = 0; d < IN_D - 1; ++d) {
            float hv = s_h[d];
            accB = fmaf(hv, iw0[(1 + d) * HID + n], accB);
            acc0 = fmaf(hv, nw0[d * HID + n], acc0);
        }
        ws[WS_BASE + b * HID + n] = accB;
        s_o0[n] = fmaxf(acc0, 0.0f);
    }
    __syncthreads();
    if (act) {
        float acc1 = nb1[n];
        for (int m = 0; m < HID; ++m)
            acc1 = fmaf(s_o0[m], nw1[m * HID + n], acc1);
        o1 = fmaxf(acc1, 0.0f);
    }
    float p0 = act ? o1 * nw2[n * 2 + 0] : 0.0f;
    float p1 = act ? o1 * nw2[n * 2 + 1] : 0.0f;
    for (int off = 32; off > 0; off >>= 1) {
        p0 += __shfl_down(p0, off);
        p1 += __shfl_down(p1, off);
    }
    int lane = tid & 63, w = tid >> 6;
    if (lane == 0 && w < 2) { s_part[w * 2] = p0; s_part[w * 2 + 1] = p1; }
    __syncthreads();
    if (tid == 0) {
        ws[WS_OFF + b]  = s_part[0] + s_part[2] + nb2[0];
        ws[WS_SCAL + b] = expf(s_part[1] + s_part[3] + nb2[1]);
    }
}

// ---------------- main MFMA kernel: 2-wave blocks, halved LDS sharing -------
// 1024 blocks of 2 waves. Wave w: builds kk {2w,2w+1} (cvt_pk), consumes
// n-half w (Af 64 regs, 4 b128 reads/tile, 16 MFMAs). ~180 regs -> 2/SIMD
// from different blocks (no cross-block barriers). Phase 2: bulk elu+weights.
__global__ __launch_bounds__(128, 2) void k3_mfma(
        const float* __restrict__ x,
        const float* __restrict__ iw0,   // row 0 = w0 (128 floats)
        const float* __restrict__ ib1,
        const float* __restrict__ iw2,
        const float* __restrict__ ib2,
        float* __restrict__ ws) {
    __shared__ bf16x8 bfr_lds[4][4][64];    // [tile][kk][lane], 16 KB
    __shared__ float zlds[2][NUMAX][17];    // [wave][u][col]
    __shared__ float s_tbl[NUMAX][16];      // MLP input s per (u, col)
    __shared__ float w_tbl[NUMAX][16];      // cc_i*cc_j*(xmax-t_i) per (u, col)
    __shared__ float s_red[2];

    int blk  = blockIdx.x;
    int b    = blk >> 2;
    int c    = blk & 3;
    int tid  = threadIdx.x;          // 0..127
    int wave = tid >> 6;             // 0 or 1
    int lane = tid & 63;
    int col  = lane & 15;
    int g    = lane >> 4;            // 0..3

    float xmax = ws[WS_XMAX];
    float xb   = x[b];
    float b2   = ib2[0];

    int NU = (c < 3) ? 41 : 40;      // tiles this chunk: t = c + 4u
    int G  = (NU + 3) >> 2;          // 11 or 10 groups

    // ---- per-block geometry tables (one pass, 128 threads) ----
    for (int e = tid; e < NU * 16; e += 128) {
        int u  = e >> 4;
        int cl = e & 15;
        int p  = (c + 4 * u) * 16 + cl;
        int pc = (p < NPTS) ? p : (NPTS - 1);
        int i  = (int)(((unsigned)pc * 10281u) >> 19);   // pc / 51
        int j  = pc - i * 51;
        float sti = ws[WS_STEPS + i];
        float stj = ws[WS_STEPS + j];
        float ti  = xb * (sti + 1.0f) * 0.5f;
        float w   = xmax - ti;
        s_tbl[u][cl] = fmaf(w, (stj + 1.0f) * 0.5f, ti);
        w_tbl[u][cl] = ws[WS_CC + i] * ws[WS_CC + j] * w;
    }

    // W1 A-fragments for this wave's 4 n-tiles (n-half): 64 regs
    const bf16x8* w1f = (const bf16x8*)(ws + WS_W1BF);
    bf16x8 Af[4][4];
#pragma unroll
    for (int nt = 0; nt < 4; ++nt) {
        int NT = wave * 4 + nt;
#pragma unroll
        for (int kk = 0; kk < 4; ++kk)
            Af[nt][kk] = w1f[(NT * 4 + kk) * 64 + lane];
    }

    // builder operands for kk0 = wave*2 and kk0+1: m = kk*32 + g*8 + e : 32 regs
    const float* basep = ws + WS_BASE + b * HID;
    int kk0 = wave * 2;
    int mA = kk0 * 32 + g * 8;           // first kk
    int mB = mA + 32;                    // second kk
    f32x4 w0A0 = *(const f32x4*)(iw0 + mA);
    f32x4 w0A1 = *(const f32x4*)(iw0 + mA + 4);
    f32x4 bsA0 = *(const f32x4*)(basep + mA);
    f32x4 bsA1 = *(const f32x4*)(basep + mA + 4);
    f32x4 w0B0 = *(const f32x4*)(iw0 + mB);
    f32x4 w0B1 = *(const f32x4*)(iw0 + mB + 4);
    f32x4 bsB0 = *(const f32x4*)(basep + mB);
    f32x4 bsB1 = *(const f32x4*)(basep + mB + 4);

    // consumer operands: ib1 (C-init) + iw2 for n = (wave*4+nt)*16 + g*4 + q : 32 regs
    f32x4 accInit[4], iw2v[4];
#pragma unroll
    for (int nt = 0; nt < 4; ++nt) {
        int n0 = (wave * 4 + nt) * 16 + g * 4;
        accInit[nt] = *(const f32x4*)(ib1 + n0);
        iw2v[nt]    = *(const f32x4*)(iw2 + n0);
    }

    __syncthreads();                 // tables ready

    for (int grp = 0; grp < G; ++grp) {
        int ubase = grp * 4;
        // ---- build group: wave w writes kk0, kk0+1 fragments (cvt_pk) ----
#pragma unroll
        for (int t = 0; t < 4; ++t) {
            int u = ubase + t;
            if (u < NU) {
                float s = s_tbl[u][col];
                u32x4 pkA, pkB;
                {
                    float v0 = fmaxf(fmaf(s, w0A0[0], bsA0[0]), 0.0f);
                    float v1 = fmaxf(fmaf(s, w0A0[1], bsA0[1]), 0.0f);
                    float v2 = fmaxf(fmaf(s, w0A0[2], bsA0[2]), 0.0f);
                    float v3 = fmaxf(fmaf(s, w0A0[3], bsA0[3]), 0.0f);
                    float v4 = fmaxf(fmaf(s, w0A1[0], bsA1[0]), 0.0f);
                    float v5 = fmaxf(fmaf(s, w0A1[1], bsA1[1]), 0.0f);
                    float v6 = fmaxf(fmaf(s, w0A1[2], bsA1[2]), 0.0f);
                    float v7 = fmaxf(fmaf(s, w0A1[3], bsA1[3]), 0.0f);
                    pkA[0] = cvt_pk_bf16(v0, v1);
                    pkA[1] = cvt_pk_bf16(v2, v3);
                    pkA[2] = cvt_pk_bf16(v4, v5);
                    pkA[3] = cvt_pk_bf16(v6, v7);
                }
                {
                    float v0 = fmaxf(fmaf(s, w0B0[0], bsB0[0]), 0.0f);
                    float v1 = fmaxf(fmaf(s, w0B0[1], bsB0[1]), 0.0f);
                    float v2 = fmaxf(fmaf(s, w0B0[2], bsB0[2]), 0.0f);
                    float v3 = fmaxf(fmaf(s, w0B0[3], bsB0[3]), 0.0f);
                    float v4 = fmaxf(fmaf(s, w0B1[0], bsB1[0]), 0.0f);
                    float v5 = fmaxf(fmaf(s, w0B1[1], bsB1[1]), 0.0f);
                    float v6 = fmaxf(fmaf(s, w0B1[2], bsB1[2]), 0.0f);
                    float v7 = fmaxf(fmaf(s, w0B1[3], bsB1[3]), 0.0f);
                    pkB[0] = cvt_pk_bf16(v0, v1);
                    pkB[1] = cvt_pk_bf16(v2, v3);
                    pkB[2] = cvt_pk_bf16(v4, v5);
                    pkB[3] = cvt_pk_bf16(v6, v7);
                }
                bfr_lds[t][kk0][lane]     = __builtin_bit_cast(bf16x8, pkA);
                bfr_lds[t][kk0 + 1][lane] = __builtin_bit_cast(bf16x8, pkB);
            }
        }
        __syncthreads();
        // ---- consume group: wave w does its 4 n-tiles ----
#pragma unroll
        for (int t = 0; t < 4; ++t) {
            int u = ubase + t;
            if (u < NU) {
                bf16x8 f0 = bfr_lds[t][0][lane];
                bf16x8 f1 = bfr_lds[t][1][lane];
                bf16x8 f2 = bfr_lds[t][2][lane];
                bf16x8 f3 = bfr_lds[t][3][lane];
                f32x4 acc[4];
#pragma unroll
                for (int nt = 0; nt < 4; ++nt)
                    acc[nt] = __builtin_amdgcn_mfma_f32_16x16x32_bf16(Af[nt][0], f0, accInit[nt], 0, 0, 0);
#pragma unroll
                for (int nt = 0; nt < 4; ++nt)
                    acc[nt] = __builtin_amdgcn_mfma_f32_16x16x32_bf16(Af[nt][1], f1, acc[nt], 0, 0, 0);
#pragma unroll
                for (int nt = 0; nt < 4; ++nt)
                    acc[nt] = __builtin_amdgcn_mfma_f32_16x16x32_bf16(Af[nt][2], f2, acc[nt], 0, 0, 0);
#pragma unroll
                for (int nt = 0; nt < 4; ++nt)
                    acc[nt] = __builtin_amdgcn_mfma_f32_16x16x32_bf16(Af[nt][3], f3, acc[nt], 0, 0, 0);

                float za = 0.f, zb = 0.f;
#pragma unroll
                for (int q = 0; q < 4; ++q) {
                    za = fmaf(fmaxf(acc[0][q], 0.0f), iw2v[0][q], za);
                    zb = fmaf(fmaxf(acc[1][q], 0.0f), iw2v[1][q], zb);
                    za = fmaf(fmaxf(acc[2][q], 0.0f), iw2v[2][q], za);
                    zb = fmaf(fmaxf(acc[3][q], 0.0f), iw2v[3][q], zb);
                }
                float z = za + zb;
                z += __shfl_xor(z, 16);
                z += __shfl_xor(z, 32);       // sum over this wave's 64 n-values
                if (lane < 16) zlds[wave][u][lane] = z;
            }
        }
        __syncthreads();
    }

    // ---- phase 2: bulk elu + weighting from tables ----
    float vsum = 0.0f;
    int npass = (NU + 7) >> 3;       // 6 or 5
    for (int pass = 0; pass < npass; ++pass) {
        int u = pass * 8 + wave * 4 + g;
        if (u < NU) {
            int p = (c + 4 * u) * 16 + col;
            if (p < NPTS) {
                float z = zlds[0][u][col] + zlds[1][u][col] + b2;
                float f = (z > 0.0f) ? (z + 1.0f) : __expf(z);
                vsum += w_tbl[u][col] * f;
            }
        }
    }
    // wave reduction, then cross-wave combine; inner weight /2 -> x0.5
#pragma unroll
    for (int off = 1; off < 64; off <<= 1)
        vsum += __shfl_xor(vsum, off);
    if (lane == 0) s_red[wave] = vsum;
    __syncthreads();
    if (tid == 0)
        ws[WS_PART + blk] = (s_red[0] + s_red[1]) * 0.5f;
}

// ---------------- final: out[b] = scal*(sum parts)*x/2 + off ----------------
__global__ void k4_final(const float* __restrict__ x, const float* __restrict__ ws,
                         float* __restrict__ out) {
    int b = threadIdx.x;
    float sum = 0.0f;
#pragma unroll
    for (int c = 0; c < 4; ++c) sum += ws[WS_PART + b * 4 + c];
    out[b] = ws[WS_SCAL + b] * sum * x[b] * 0.5f + ws[WS_OFF + b];
}

extern "C" void kernel_launch(void* const* d_in, const int* in_sizes, int n_in,
                              void* d_out, int out_size, void* d_ws, size_t ws_size,
                              hipStream_t stream) {
    const float* x   = (const float*)d_in[0];
    const float* h   = (const float*)d_in[1];
    const float* iw0 = (const float*)d_in[2];
    const float* ib0 = (const float*)d_in[3];
    const float* iw1 = (const float*)d_in[4];
    const float* ib1 = (const float*)d_in[5];
    const float* iw2 = (const float*)d_in[6];
    const float* ib2 = (const float*)d_in[7];
    const float* nw0 = (const float*)d_in[8];
    const float* nb0 = (const float*)d_in[9];
    const float* nw1 = (const float*)d_in[10];
    const float* nb1 = (const float*)d_in[11];
    const float* nw2 = (const float*)d_in[12];
    const float* nb2 = (const float*)d_in[13];
    float* ws  = (float*)d_ws;
    float* out = (float*)d_out;

    hipLaunchKernelGGL(k_prep, dim3(64 + 1 + BSZ), dim3(256), 0, stream,
                       x, h, iw0, ib0, iw1, nw0, nb0, nw1, nb1, nw2, nb2, ws);
    hipLaunchKernelGGL(k3_mfma, dim3(BSZ * NCHUNK), dim3(128), 0, stream,
                       x, iw0, ib1, iw2, ib2, ws);
    hipLaunchKernelGGL(k4_final, dim3(1), dim3(BSZ), 0, stream, x, ws, out);
}

// Round 12
// 49.440 us; speedup vs baseline: 1.0397x; 1.0397x over previous
//
#include <hip/hip_runtime.h>
#include <math.h>

#define NBQ 50
#define S1 51
#define NPTS 2601      // 51*51
#define IN_D 64
#define HID 128
#define BSZ 256
#define NCHUNK 4
#define NUMAX 41       // max tiles per chunk (c<3: 41, c==3: 40)

typedef __bf16 bf16x8 __attribute__((ext_vector_type(8)));
typedef float  f32x4  __attribute__((ext_vector_type(4)));

// ws layout (floats)
#define WS_CC     0                    // 51
#define WS_STEPS  64                   // 51
#define WS_XMAX   128                  // 1
#define WS_BASE   256                  // 256*128 = 32768
#define WS_SCAL   33024                // 256
#define WS_OFF    33280                // 256
#define WS_PART   33536                // 1024 blocks * 4 waves = 4096
#define WS_W1BF   41728                // 16384 bf16 = 8192 floats -> ends 49920

// ---------------- prep: w1 fragment conversion + cc/steps/xmax + base + n-net
__global__ void k_prep(const float* __restrict__ x, const float* __restrict__ h,
                       const float* __restrict__ iw0, const float* __restrict__ ib0,
                       const float* __restrict__ iw1,
                       const float* __restrict__ nw0, const float* __restrict__ nb0,
                       const float* __restrict__ nw1, const float* __restrict__ nb1,
                       const float* __restrict__ nw2, const float* __restrict__ nb2,
                       float* __restrict__ ws) {
    int blk = blockIdx.x;
    int tid = threadIdx.x;

    if (blk < 64) {
        // A-frag order: idx = ((NT*4+kk)*64 + lane)*8 + e
        //  value = iw1[(kk*32 + (lane>>4)*8 + e)*128 + NT*16 + (lane&15)]
        int idx  = blk * 256 + tid;      // 0..16383
        int e    = idx & 7;
        int lane = (idx >> 3) & 63;
        int fk   = idx >> 9;             // 0..31
        int kk   = fk & 3;
        int nt   = fk >> 2;
        int k = kk * 32 + (lane >> 4) * 8 + e;
        int n = nt * 16 + (lane & 15);
        __bf16* w1bf = (__bf16*)(ws + WS_W1BF);
        w1bf[idx] = (__bf16)iw1[k * HID + n];
        return;
    }

    __shared__ float s_steps[S1];
    __shared__ float s_red[4];
    __shared__ float s_h[IN_D - 1];
    __shared__ float s_o0[HID];
    __shared__ float s_part[4];

    if (blk == 64) {
        int t = tid;
        if (t < S1) {
            double st = cos((double)t * M_PI / (double)NBQ);
            s_steps[t] = (float)st;
            ws[WS_STEPS + t] = (float)st;
            double acc = 0.0;
            for (int i = 0; i <= NBQ; ++i) {
                double Wi;
                if (i == 0)       Wi = 1.0;
                else if (i & 1)   Wi = 0.0;
                else              Wi = 2.0 / (1.0 - (double)i * (double)i);
                double lam;
                if (t == 0)  lam = 0.5;
                else         lam = cos((double)i * (double)t * M_PI / (double)NBQ);
                if (t == NBQ) lam *= 0.5;
                lam *= 2.0 / (double)NBQ;
                acc += lam * Wi;
            }
            ws[WS_CC + t] = (float)acc;
        }
        __syncthreads();
        float xb = x[t];
        float m = -1e30f;
        for (int i = 0; i < S1; ++i)
            m = fmaxf(m, xb * (s_steps[i] + 1.0f) * 0.5f);
        for (int off = 32; off > 0; off >>= 1)
            m = fmaxf(m, __shfl_down(m, off));
        if ((t & 63) == 0) s_red[t >> 6] = m;
        __syncthreads();
        if (t == 0) {
            float mm = fmaxf(fmaxf(s_red[0], s_red[1]), fmaxf(s_red[2], s_red[3]));
            ws[WS_XMAX] = mm + 10.0f;
        }
        return;
    }

    // ---- base[b] + n-network: b = blk - 65, first 128 threads active ----
    int b = blk - 65;
    int n = tid;
    bool act = (n < HID);
    if (act && n < IN_D - 1) s_h[n] = h[b * (IN_D - 1) + n];
    __syncthreads();
    float o1 = 0.0f;
    if (act) {
        // 4 independent partial chains over d (63 iters)
        float aB0 = ib0[n], aB1 = 0.f, aB2 = 0.f, aB3 = 0.f;
        float a00 = nb0[n], a01 = 0.f, a02 = 0.f, a03 = 0.f;
        int d = 0;
        for (; d + 4 <= IN_D - 1; d += 4) {
            float h0 = s_h[d], h1 = s_h[d + 1], h2 = s_h[d + 2], h3 = s_h[d + 3];
            aB0 = fmaf(h0, iw0[(1 + d) * HID + n], aB0);
            aB1 = fmaf(h1, iw0[(2 + d) * HID + n], aB1);
            aB2 = fmaf(h2, iw0[(3 + d) * HID + n], aB2);
            aB3 = fmaf(h3, iw0[(4 + d) * HID + n], aB3);
            a00 = fmaf(h0, nw0[(d)     * HID + n], a00);
            a01 = fmaf(h1, nw0[(d + 1) * HID + n], a01);
            a02 = fmaf(h2, nw0[(d + 2) * HID + n], a02);
            a03 = fmaf(h3, nw0[(d + 3) * HID + n], a03);
        }
        for (; d < IN_D - 1; ++d) {
            float hv = s_h[d];
            aB0 = fmaf(hv, iw0[(1 + d) * HID + n], aB0);
            a00 = fmaf(hv, nw0[d * HID + n], a00);
        }
        float accB = (aB0 + aB1) + (aB2 + aB3);
        float acc0 = (a00 + a01) + (a02 + a03);
        ws[WS_BASE + b * HID + n] = accB;
        s_o0[n] = fmaxf(acc0, 0.0f);
    }
    __syncthreads();
    if (act) {
        float a0 = nb1[n], a1 = 0.f, a2 = 0.f, a3 = 0.f;
        for (int m = 0; m < HID; m += 4) {
            a0 = fmaf(s_o0[m],     nw1[(m)     * HID + n], a0);
            a1 = fmaf(s_o0[m + 1], nw1[(m + 1) * HID + n], a1);
            a2 = fmaf(s_o0[m + 2], nw1[(m + 2) * HID + n], a2);
            a3 = fmaf(s_o0[m + 3], nw1[(m + 3) * HID + n], a3);
        }
        o1 = fmaxf((a0 + a1) + (a2 + a3), 0.0f);
    }
    float p0 = act ? o1 * nw2[n * 2 + 0] : 0.0f;
    float p1 = act ? o1 * nw2[n * 2 + 1] : 0.0f;
    for (int off = 32; off > 0; off >>= 1) {
        p0 += __shfl_down(p0, off);
        p1 += __shfl_down(p1, off);
    }
    int lane = tid & 63, w = tid >> 6;
    if (lane == 0 && w < 2) { s_part[w * 2] = p0; s_part[w * 2 + 1] = p1; }
    __syncthreads();
    if (tid == 0) {
        ws[WS_OFF + b]  = s_part[0] + s_part[2] + nb2[0];
        ws[WS_SCAL + b] = expf(s_part[1] + s_part[3] + nb2[1]);
    }
}

// ---------------- main MFMA kernel: R10 structure + s_setprio ----------------
// 1024 blocks (b x 4 chunks) of 4 waves, 4 blocks/CU. Per 4-tile group:
// build (wave w = kk w) -> bar -> consume (wave w = nt pair w, MFMA cluster
// wrapped in setprio(1)) -> bar. Phase 2: bulk elu+weight from tables.
__global__ __launch_bounds__(256, 4) void k3_mfma(
        const float* __restrict__ x,
        const float* __restrict__ iw0,   // row 0 = w0 (128 floats)
        const float* __restrict__ ib1,
        const float* __restrict__ iw2,
        const float* __restrict__ ib2,
        float* __restrict__ ws) {
    __shared__ bf16x8 bfr_lds[4][4][64];    // [tile][kk][lane], 16 KB
    __shared__ float zlds[4][NUMAX][17];    // [wave][u][col], 11.2 KB
    __shared__ float s_tbl[NUMAX][16];      // MLP input s per (u, col)
    __shared__ float w_tbl[NUMAX][16];      // cc_i*cc_j*(xmax-t_i) per (u, col)

    int blk  = blockIdx.x;
    int b    = blk >> 2;
    int c    = blk & 3;
    int tid  = threadIdx.x;
    int wave = tid >> 6;             // 0..3
    int lane = tid & 63;
    int col  = lane & 15;
    int g    = lane >> 4;            // 0..3

    float xmax = ws[WS_XMAX];
    float xb   = x[b];
    float b2   = ib2[0];

    int NU = (c < 3) ? 41 : 40;      // tiles this chunk: t = c + 4u
    int G  = (NU + 3) >> 2;          // 11 or 10 groups

    // ---- per-block geometry tables (one pass) ----
    for (int e = tid; e < NU * 16; e += 256) {
        int u  = e >> 4;
        int cl = e & 15;
        int p  = (c + 4 * u) * 16 + cl;
        int pc = (p < NPTS) ? p : (NPTS - 1);
        int i  = (int)(((unsigned)pc * 10281u) >> 19);   // pc / 51
        int j  = pc - i * 51;
        float sti = ws[WS_STEPS + i];
        float stj = ws[WS_STEPS + j];
        float ti  = xb * (sti + 1.0f) * 0.5f;
        float w   = xmax - ti;
        s_tbl[u][cl] = fmaf(w, (stj + 1.0f) * 0.5f, ti);
        w_tbl[u][cl] = ws[WS_CC + i] * ws[WS_CC + j] * w;
    }

    // W1 A-fragments for this wave's 2 n-tiles: 32 regs
    const bf16x8* w1f = (const bf16x8*)(ws + WS_W1BF);
    bf16x8 Af[2][4];
#pragma unroll
    for (int nt = 0; nt < 2; ++nt) {
        int NT = wave * 2 + nt;
#pragma unroll
        for (int kk = 0; kk < 4; ++kk)
            Af[nt][kk] = w1f[(NT * 4 + kk) * 64 + lane];
    }

    // builder operands: w0/base for kk = wave (m = wave*32 + g*8 + e): 16 regs
    const float* basep = ws + WS_BASE + b * HID;
    int m0 = wave * 32 + g * 8;
    f32x4 w0a = *(const f32x4*)(iw0 + m0);
    f32x4 w0b = *(const f32x4*)(iw0 + m0 + 4);
    f32x4 bsa = *(const f32x4*)(basep + m0);
    f32x4 bsb = *(const f32x4*)(basep + m0 + 4);

    // consumer operands: ib1 (C-init) + iw2 for n = (wave*2+nt)*16 + g*4 + q: 16 regs
    f32x4 accInit[2], iw2v[2];
#pragma unroll
    for (int nt = 0; nt < 2; ++nt) {
        int n0 = (wave * 2 + nt) * 16 + g * 4;
        accInit[nt] = *(const f32x4*)(ib1 + n0);
        iw2v[nt]    = *(const f32x4*)(iw2 + n0);
    }

    __syncthreads();                 // tables ready

    for (int grp = 0; grp < G; ++grp) {
        int ubase = grp * 4;
        // ---- build group ----
#pragma unroll
        for (int t = 0; t < 4; ++t) {
            int u = ubase + t;
            if (u < NU) {
                float s = s_tbl[u][col];
                bf16x8 bfr;
#pragma unroll
                for (int e = 0; e < 4; ++e) {
                    bfr[e]     = (__bf16)fmaxf(fmaf(s, w0a[e], bsa[e]), 0.0f);
                    bfr[4 + e] = (__bf16)fmaxf(fmaf(s, w0b[e], bsb[e]), 0.0f);
                }
                bfr_lds[t][wave][lane] = bfr;
            }
        }
        __syncthreads();
        // ---- consume group (MFMA cluster at raised priority) ----
#pragma unroll
        for (int t = 0; t < 4; ++t) {
            int u = ubase + t;
            if (u < NU) {
                bf16x8 f0 = bfr_lds[t][0][lane];
                bf16x8 f1 = bfr_lds[t][1][lane];
                bf16x8 f2 = bfr_lds[t][2][lane];
                bf16x8 f3 = bfr_lds[t][3][lane];
                __builtin_amdgcn_s_setprio(1);
                f32x4 a0 = __builtin_amdgcn_mfma_f32_16x16x32_bf16(Af[0][0], f0, accInit[0], 0, 0, 0);
                f32x4 a1 = __builtin_amdgcn_mfma_f32_16x16x32_bf16(Af[1][0], f0, accInit[1], 0, 0, 0);
                a0 = __builtin_amdgcn_mfma_f32_16x16x32_bf16(Af[0][1], f1, a0, 0, 0, 0);
                a1 = __builtin_amdgcn_mfma_f32_16x16x32_bf16(Af[1][1], f1, a1, 0, 0, 0);
                a0 = __builtin_amdgcn_mfma_f32_16x16x32_bf16(Af[0][2], f2, a0, 0, 0, 0);
                a1 = __builtin_amdgcn_mfma_f32_16x16x32_bf16(Af[1][2], f2, a1, 0, 0, 0);
                a0 = __builtin_amdgcn_mfma_f32_16x16x32_bf16(Af[0][3], f3, a0, 0, 0, 0);
                a1 = __builtin_amdgcn_mfma_f32_16x16x32_bf16(Af[1][3], f3, a1, 0, 0, 0);
                __builtin_amdgcn_s_setprio(0);

                float za = 0.f, zb = 0.f;
#pragma unroll
                for (int q = 0; q < 4; ++q) {
                    za = fmaf(fmaxf(a0[q], 0.0f), iw2v[0][q], za);
                    zb = fmaf(fmaxf(a1[q], 0.0f), iw2v[1][q], zb);
                }
                float z = za + zb;
                z += __shfl_xor(z, 16);
                z += __shfl_xor(z, 32);       // sum over this wave's 32 n-values
                if (lane < 16) zlds[wave][u][lane] = z;
            }
        }
        __syncthreads();
    }

    // ---- phase 2: bulk elu + weighting from tables ----
    float vsum = 0.0f;
    int npass = (NU + 15) >> 4;      // 3
    for (int pass = 0; pass < npass; ++pass) {
        int u = pass * 16 + wave * 4 + g;
        if (u < NU) {
            int p = (c + 4 * u) * 16 + col;
            if (p < NPTS) {
                float z = zlds[0][u][col] + zlds[1][u][col]
                        + zlds[2][u][col] + zlds[3][u][col] + b2;
                float f = (z > 0.0f) ? (z + 1.0f) : __expf(z);
                vsum += w_tbl[u][col] * f;
            }
        }
    }
    // wave reduction; inner weight /2 -> x0.5 (each point counted once)
#pragma unroll
    for (int off = 1; off < 64; off <<= 1)
        vsum += __shfl_xor(vsum, off);
    if (lane == 0)
        ws[WS_PART + blk * 4 + wave] = vsum * 0.5f;
}

// ---------------- final: out[b] = scal*(sum parts)*x/2 + off ----------------
__global__ void k4_final(const float* __restrict__ x, const float* __restrict__ ws,
                         float* __restrict__ out) {
    int b = threadIdx.x;
    float sum = 0.0f;
#pragma unroll
    for (int c = 0; c < 16; ++c) sum += ws[WS_PART + b * 16 + c];
    out[b] = ws[WS_SCAL + b] * sum * x[b] * 0.5f + ws[WS_OFF + b];
}

extern "C" void kernel_launch(void* const* d_in, const int* in_sizes, int n_in,
                              void* d_out, int out_size, void* d_ws, size_t ws_size,
                              hipStream_t stream) {
    const float* x   = (const float*)d_in[0];
    const float* h   = (const float*)d_in[1];
    const float* iw0 = (const float*)d_in[2];
    const float* ib0 = (const float*)d_in[3];
    const float* iw1 = (const float*)d_in[4];
    const float* ib1 = (const float*)d_in[5];
    const float* iw2 = (const float*)d_in[6];
    const float* ib2 = (const float*)d_in[7];
    const float* nw0 = (const float*)d_in[8];
    const float* nb0 = (const float*)d_in[9];
    const float* nw1 = (const float*)d_in[10];
    const float* nb1 = (const float*)d_in[11];
    const float* nw2 = (const float*)d_in[12];
    const float* nb2 = (const float*)d_in[13];
    float* ws  = (float*)d_ws;
    float* out = (float*)d_out;

    hipLaunchKernelGGL(k_prep, dim3(64 + 1 + BSZ), dim3(256), 0, stream,
                       x, h, iw0, ib0, iw1, nw0, nb0, nw1, nb1, nw2, nb2, ws);
    hipLaunchKernelGGL(k3_mfma, dim3(BSZ * NCHUNK), dim3(256), 0, stream,
                       x, iw0, ib1, iw2, ib2, ws);
    hipLaunchKernelGGL(k4_final, dim3(1), dim3(BSZ), 0, stream, x, ws, out);
}